// Round 2
// baseline (451.413 us; speedup 1.0000x reference)
//
#include <hip/hip_runtime.h>
#include <hip/hip_bf16.h>
#include <stdint.h>

typedef unsigned short u16;
typedef unsigned int   u32;

__device__ __forceinline__ float bf2f(u16 u) { return __uint_as_float(((u32)u) << 16); }
__device__ __forceinline__ u16 f2bf(float f) {
    u32 u = __float_as_uint(f);
    u += 0x7FFFu + ((u >> 16) & 1u);   // round-nearest-even
    return (u16)(u >> 16);
}

// ---------------- CSR build ----------------

__global__ void k_count(const int* __restrict__ dst, int* __restrict__ cnt, int E) {
    int i = blockIdx.x * blockDim.x + threadIdx.x;
    if (i < E) atomicAdd(&cnt[dst[i]], 1);
}

__global__ void k_scan_blocks(const int* __restrict__ cnt, int* __restrict__ rp,
                              int* __restrict__ bs, int n) {
    __shared__ int sh[1024];
    int t = threadIdx.x;
    int i = blockIdx.x * 1024 + t;
    int v = (i < n) ? cnt[i] : 0;
    sh[t] = v;
    __syncthreads();
    for (int o = 1; o < 1024; o <<= 1) {
        int x = (t >= o) ? sh[t - o] : 0;
        __syncthreads();
        sh[t] += x;
        __syncthreads();
    }
    if (i < n) rp[i] = sh[t] - v;          // exclusive scan within block
    if (t == 1023) bs[blockIdx.x] = sh[t]; // block total
}

__global__ void k_scan_sums(int* __restrict__ bs, int nb, int* __restrict__ rp, int n, int E) {
    __shared__ int sh[128];
    int t = threadIdx.x;
    if (t < nb) sh[t] = bs[t];
    __syncthreads();
    if (t == 0) {
        int run = 0;
        for (int b = 0; b < nb; b++) { int v = sh[b]; sh[b] = run; run += v; }
        rp[n] = E;
    }
    __syncthreads();
    if (t < nb) bs[t] = sh[t];
}

__global__ void k_scan_add(int* __restrict__ rp, int* __restrict__ cur,
                           const int* __restrict__ bs, int n) {
    int i = blockIdx.x * 1024 + threadIdx.x;
    if (i < n) { int v = rp[i] + bs[blockIdx.x]; rp[i] = v; cur[i] = v; }
}

__global__ void k_fill(const int* __restrict__ src, const int* __restrict__ dst,
                       int* __restrict__ cur, int* __restrict__ col, int E) {
    int i = blockIdx.x * blockDim.x + threadIdx.x;
    if (i < E) { int p = atomicAdd(&cur[dst[i]], 1); col[p] = src[i]; }
}

// ---------------- Layer 1 dense: Z = X@Ws1 + b1 (f32), Y = X@Wn1 (bf16) ----------
// One wave per node; lane j produces output column j of both Ws1 and Wn1.
// Weights staged in LDS as float2 pairs (ds_read_b64; 2-way conflict is free).

__global__ __launch_bounds__(256) void k_gemm1(const float* __restrict__ X,
                                               const float* __restrict__ Ws,
                                               const float* __restrict__ b1,
                                               const float* __restrict__ Wn,
                                               float* __restrict__ Z,
                                               u16* __restrict__ Y, int n) {
    __shared__ float2 pw[64 * 64];  // 32 KiB
    int t = threadIdx.x;
    for (int i = t; i < 4096; i += 256)
        pw[i] = make_float2(Ws[i], Wn[i]);
    __syncthreads();

    int wid = t >> 6, lane = t & 63;
    float bias = b1[lane];
    int stride = gridDim.x * 4;
    for (int node = blockIdx.x * 4 + wid; node < n; node += stride) {
        float x = X[node * 64 + lane];
        float az = 0.f, ay = 0.f;
#pragma unroll
        for (int k = 0; k < 64; k++) {
            float xk = __shfl(x, k, 64);
            float2 w = pw[k * 64 + lane];
            az += xk * w.x;
            ay += xk * w.y;
        }
        Z[node * 64 + lane] = az + bias;
        Y[node * 64 + lane] = f2bf(ay);
    }
}

// ---------------- Layer 1 aggregate: h1 = tanh(Z + mean(Y[neigh])) ----------------
// One wave per node; each neighbor row is one coalesced 128B line (bf16).

__global__ __launch_bounds__(256) void k_gather1(const int* __restrict__ rp,
                                                 const int* __restrict__ col,
                                                 const float* __restrict__ Z,
                                                 const u16* __restrict__ Y,
                                                 u16* __restrict__ H1, int n) {
    int t = threadIdx.x;
    int wid = t >> 6, lane = t & 63;
    int node = blockIdx.x * 4 + wid;
    if (node >= n) return;
    int beg = rp[node], end = rp[node + 1];
    float acc = 0.f;
    int e = beg;
    for (; e + 4 <= end; e += 4) {
        int s0 = col[e], s1 = col[e + 1], s2 = col[e + 2], s3 = col[e + 3];
        float a = bf2f(Y[s0 * 64 + lane]);
        float b = bf2f(Y[s1 * 64 + lane]);
        float c = bf2f(Y[s2 * 64 + lane]);
        float d = bf2f(Y[s3 * 64 + lane]);
        acc += (a + b) + (c + d);
    }
    for (; e < end; e++) acc += bf2f(Y[col[e] * 64 + lane]);
    float deg = (float)(end - beg);
    float hn = (deg > 0.f) ? acc / deg : 0.f;
    float h = Z[node * 64 + lane] + hn;
    H1[node * 64 + lane] = f2bf(tanhf(h));
}

// ---------------- Layer 2 dense: P = h1@Ws2 + b2 (f32), Q = h1@Wn2 (bf16) --------

__global__ __launch_bounds__(128) void k_gemm2(const u16* __restrict__ H1,
                                               const float* __restrict__ Ws2,
                                               const float* __restrict__ b2,
                                               const float* __restrict__ Wn2,
                                               float* __restrict__ P,
                                               u16* __restrict__ Q, int n) {
    __shared__ float ws[256], wn[256], bb[4];
    int t = threadIdx.x;
    for (int i = t; i < 256; i += 128) { ws[i] = Ws2[i]; wn[i] = Wn2[i]; }
    if (t < 4) bb[t] = b2[t];
    __syncthreads();

    int node = blockIdx.x * 128 + t;
    if (node >= n) return;
    const u16* row = H1 + node * 64;
    float p0 = bb[0], p1 = bb[1], p2 = bb[2], p3 = bb[3];
    float q0 = 0.f, q1 = 0.f, q2 = 0.f, q3 = 0.f;
#pragma unroll
    for (int k = 0; k < 64; k += 4) {
        ushort4 hv = *(const ushort4*)(row + k);
        float h0 = bf2f(hv.x), h1v = bf2f(hv.y), h2 = bf2f(hv.z), h3 = bf2f(hv.w);
        const float* w;
        w = &ws[(k + 0) * 4]; p0 += h0 * w[0]; p1 += h0 * w[1]; p2 += h0 * w[2]; p3 += h0 * w[3];
        w = &wn[(k + 0) * 4]; q0 += h0 * w[0]; q1 += h0 * w[1]; q2 += h0 * w[2]; q3 += h0 * w[3];
        w = &ws[(k + 1) * 4]; p0 += h1v * w[0]; p1 += h1v * w[1]; p2 += h1v * w[2]; p3 += h1v * w[3];
        w = &wn[(k + 1) * 4]; q0 += h1v * w[0]; q1 += h1v * w[1]; q2 += h1v * w[2]; q3 += h1v * w[3];
        w = &ws[(k + 2) * 4]; p0 += h2 * w[0]; p1 += h2 * w[1]; p2 += h2 * w[2]; p3 += h2 * w[3];
        w = &wn[(k + 2) * 4]; q0 += h2 * w[0]; q1 += h2 * w[1]; q2 += h2 * w[2]; q3 += h2 * w[3];
        w = &ws[(k + 3) * 4]; p0 += h3 * w[0]; p1 += h3 * w[1]; p2 += h3 * w[2]; p3 += h3 * w[3];
        w = &wn[(k + 3) * 4]; q0 += h3 * w[0]; q1 += h3 * w[1]; q2 += h3 * w[2]; q3 += h3 * w[3];
    }
    *(float4*)(P + node * 4) = make_float4(p0, p1, p2, p3);
    ushort4 qv; qv.x = f2bf(q0); qv.y = f2bf(q1); qv.z = f2bf(q2); qv.w = f2bf(q3);
    *(ushort4*)(Q + node * 4) = qv;
}

// ---------------- Layer 2 aggregate: out = P + mean(Q[neigh])  (f32 out) ---------

__global__ __launch_bounds__(256) void k_gather2(const int* __restrict__ rp,
                                                 const int* __restrict__ col,
                                                 const float* __restrict__ P,
                                                 const u16* __restrict__ Q,
                                                 float* __restrict__ out, int n) {
    int node = blockIdx.x * 256 + threadIdx.x;
    if (node >= n) return;
    int beg = rp[node], end = rp[node + 1];
    float a0 = 0.f, a1 = 0.f, a2 = 0.f, a3 = 0.f;
    for (int e = beg; e < end; e++) {
        int s = col[e];
        ushort4 q = *(const ushort4*)(Q + s * 4);
        a0 += bf2f(q.x); a1 += bf2f(q.y); a2 += bf2f(q.z); a3 += bf2f(q.w);
    }
    float deg = (float)(end - beg);
    float inv = (deg > 0.f) ? 1.f / deg : 0.f;
    float4 p = *(const float4*)(P + node * 4);
    float4 o = make_float4(p.x + a0 * inv, p.y + a1 * inv,
                           p.z + a2 * inv, p.w + a3 * inv);
    *(float4*)(out + node * 4) = o;
}

// ---------------- launch ----------------

extern "C" void kernel_launch(void* const* d_in, const int* in_sizes, int n_in,
                              void* d_out, int out_size, void* d_ws, size_t ws_size,
                              hipStream_t stream) {
    const float* X   = (const float*)d_in[0];
    const int* esrc  = (const int*)d_in[1];
    const int* edst  = (const int*)d_in[2];
    const float* Ws1 = (const float*)d_in[3];
    const float* b1  = (const float*)d_in[4];
    const float* Wn1 = (const float*)d_in[5];
    const float* Ws2 = (const float*)d_in[6];
    const float* b2  = (const float*)d_in[7];
    const float* Wn2 = (const float*)d_in[8];
    float* out = (float*)d_out;

    const int n = in_sizes[0] / 64;   // 100000
    const int E = in_sizes[1];        // 1600000

    size_t off = 0;
    char* base = (char*)d_ws;
    auto give = [&](size_t bytes) -> char* {
        char* p = base + off;
        off += (bytes + 255) & ~(size_t)255;
        return p;
    };
    int*   row_ptr = (int*)give((size_t)(n + 1) * 4);
    int*   cursor  = (int*)give((size_t)n * 4);
    int*   bsums   = (int*)give(1024);
    int*   col     = (int*)give((size_t)E * 4);
    float* Z       = (float*)give((size_t)n * 64 * 4);
    u16*   Y       = (u16*)give((size_t)n * 64 * 2);
    u16*   H1      = (u16*)give((size_t)n * 64 * 2);
    float* P       = (float*)give((size_t)n * 4 * 4);
    u16*   Q       = (u16*)give((size_t)n * 4 * 2);

    // --- CSR build (per launch; ws is re-poisoned before every call) ---
    hipMemsetAsync(cursor, 0, (size_t)n * 4, stream);
    k_count<<<(E + 255) / 256, 256, 0, stream>>>(edst, cursor, E);
    int nb = (n + 1023) / 1024;  // 98
    k_scan_blocks<<<nb, 1024, 0, stream>>>(cursor, row_ptr, bsums, n);
    k_scan_sums<<<1, 128, 0, stream>>>(bsums, nb, row_ptr, n, E);
    k_scan_add<<<nb, 1024, 0, stream>>>(row_ptr, cursor, bsums, n);
    k_fill<<<(E + 255) / 256, 256, 0, stream>>>(esrc, edst, cursor, col, E);

    // --- Layer 1 ---
    k_gemm1<<<1280, 256, 0, stream>>>(X, Ws1, b1, Wn1, Z, Y, n);
    k_gather1<<<(n + 3) / 4, 256, 0, stream>>>(row_ptr, col, Z, Y, H1, n);

    // --- Layer 2 ---
    k_gemm2<<<(n + 127) / 128, 128, 0, stream>>>(H1, Ws2, b2, Wn2, P, Q, n);
    k_gather2<<<(n + 255) / 256, 256, 0, stream>>>(row_ptr, col, P, Q, out, n);
}

// Round 3
// 313.251 us; speedup vs baseline: 1.4411x; 1.4411x over previous
//
#include <hip/hip_runtime.h>
#include <hip/hip_bf16.h>
#include <stdint.h>

typedef unsigned short u16;
typedef unsigned int   u32;

#define MAXB 256          // max buckets (n<=131072 with 512-node buckets)
#define BKT_SHIFT 9       // 512 nodes per bucket
#define BKT_NODES 512

__device__ __forceinline__ float bf2f(u16 u) { return __uint_as_float(((u32)u) << 16); }
__device__ __forceinline__ u16 f2bf(float f) {
    u32 u = __float_as_uint(f);
    u += 0x7FFFu + ((u >> 16) & 1u);   // round-nearest-even
    return (u16)(u >> 16);
}

// ---------------- bucketed CSR build ----------------
// bucket b = dst >> 9. Phase 1: global per-bucket histogram.

__global__ __launch_bounds__(256) void k_hist(const int* __restrict__ dst,
                                              int* __restrict__ gcnt,
                                              int E, int chunk, int nb) {
    __shared__ int h[MAXB];
    int t = threadIdx.x;
    for (int i = t; i < nb; i += 256) h[i] = 0;
    __syncthreads();
    int beg = blockIdx.x * chunk, end = min(beg + chunk, E);
    for (int i = beg + t; i < end; i += 256) atomicAdd(&h[dst[i] >> BKT_SHIFT], 1);
    __syncthreads();
    for (int i = t; i < nb; i += 256) { int c = h[i]; if (c) atomicAdd(&gcnt[i], c); }
}

// Phase 2: tiny exclusive scan of bucket counts.
__global__ void k_bscan(const int* __restrict__ gcnt, int* __restrict__ boff,
                        int* __restrict__ gcur, int* __restrict__ rp,
                        int nb, int n, int E) {
    __shared__ int s[MAXB];
    int t = threadIdx.x;
    if (t < nb) s[t] = gcnt[t];
    __syncthreads();
    if (t == 0) {
        int run = 0;
        for (int b = 0; b < nb; b++) { int v = s[b]; s[b] = run; run += v; }
        rp[n] = E;
    }
    __syncthreads();
    if (t < nb) { boff[t] = s[t]; gcur[t] = s[t]; }
}

// Phase 3: bin edges into dense per-bucket regions, packed (src<<9)|dstLocal.
__global__ __launch_bounds__(256) void k_bin(const int* __restrict__ src,
                                             const int* __restrict__ dst,
                                             int* __restrict__ gcur,
                                             u32* __restrict__ binned,
                                             int E, int chunk, int nb) {
    __shared__ int h[MAXB], base[MAXB], lcur[MAXB];
    int t = threadIdx.x;
    for (int i = t; i < nb; i += 256) h[i] = 0;
    __syncthreads();
    int beg = blockIdx.x * chunk, end = min(beg + chunk, E);
    for (int i = beg + t; i < end; i += 256) atomicAdd(&h[dst[i] >> BKT_SHIFT], 1);
    __syncthreads();
    for (int i = t; i < nb; i += 256) {
        int c = h[i];
        base[i] = c ? atomicAdd(&gcur[i], c) : 0;
        lcur[i] = 0;
    }
    __syncthreads();
    for (int i = beg + t; i < end; i += 256) {
        int d = dst[i], b = d >> BKT_SHIFT;
        int p = atomicAdd(&lcur[b], 1);
        binned[base[b] + p] = ((u32)src[i] << BKT_SHIFT) | (u32)(d & (BKT_NODES - 1));
    }
}

// Phase 4: per-bucket local CSR — row_ptr + dense col fill.
__global__ __launch_bounds__(512) void k_csr(const u32* __restrict__ binned,
                                             const int* __restrict__ boff,
                                             int* __restrict__ rp,
                                             int* __restrict__ col,
                                             int nb, int n, int E) {
    __shared__ int cnt[BKT_NODES], tmp[BKT_NODES];
    int b = blockIdx.x, t = threadIdx.x;
    int ebeg = boff[b];
    int eend = (b + 1 < nb) ? boff[b + 1] : E;
    cnt[t] = 0;
    __syncthreads();
    for (int i = ebeg + t; i < eend; i += 512)
        atomicAdd(&cnt[binned[i] & (BKT_NODES - 1)], 1);
    __syncthreads();
    int v = cnt[t];
    tmp[t] = v;
    __syncthreads();
    for (int o = 1; o < BKT_NODES; o <<= 1) {
        int y = (t >= o) ? tmp[t - o] : 0;
        __syncthreads();
        tmp[t] += y;
        __syncthreads();
    }
    int excl = tmp[t] - v;
    int gnode = b * BKT_NODES + t;
    if (gnode < n) rp[gnode] = ebeg + excl;
    cnt[t] = excl;   // reuse as cursor
    __syncthreads();
    for (int i = ebeg + t; i < eend; i += 512) {
        u32 e = binned[i];
        int p = atomicAdd(&cnt[e & (BKT_NODES - 1)], 1);
        col[ebeg + p] = (int)(e >> BKT_SHIFT);
    }
}

// ---------------- Layer 1 dense: Z = X@Ws1 + b1 (f32), Y = X@Wn1 (bf16) ----------

__global__ __launch_bounds__(256) void k_gemm1(const float* __restrict__ X,
                                               const float* __restrict__ Ws,
                                               const float* __restrict__ b1,
                                               const float* __restrict__ Wn,
                                               float* __restrict__ Z,
                                               u16* __restrict__ Y, int n) {
    __shared__ float2 pw[64 * 64];  // 32 KiB
    int t = threadIdx.x;
    for (int i = t; i < 4096; i += 256)
        pw[i] = make_float2(Ws[i], Wn[i]);
    __syncthreads();

    int wid = t >> 6, lane = t & 63;
    float bias = b1[lane];
    int stride = gridDim.x * 4;
    for (int node = blockIdx.x * 4 + wid; node < n; node += stride) {
        float x = X[node * 64 + lane];
        float az = 0.f, ay = 0.f;
#pragma unroll
        for (int k = 0; k < 64; k++) {
            float xk = __shfl(x, k, 64);
            float2 w = pw[k * 64 + lane];
            az += xk * w.x;
            ay += xk * w.y;
        }
        Z[node * 64 + lane] = az + bias;
        Y[node * 64 + lane] = f2bf(ay);
    }
}

// ---------------- Layer 1 aggregate: h1 = tanh(Z + mean(Y[neigh])) ----------------

__global__ __launch_bounds__(256) void k_gather1(const int* __restrict__ rp,
                                                 const int* __restrict__ col,
                                                 const float* __restrict__ Z,
                                                 const u16* __restrict__ Y,
                                                 u16* __restrict__ H1, int n) {
    int t = threadIdx.x;
    int wid = t >> 6, lane = t & 63;
    int node = blockIdx.x * 4 + wid;
    if (node >= n) return;
    int beg = rp[node], end = rp[node + 1];
    float acc = 0.f;
    int e = beg;
    for (; e + 4 <= end; e += 4) {
        int s0 = col[e], s1 = col[e + 1], s2 = col[e + 2], s3 = col[e + 3];
        float a = bf2f(Y[s0 * 64 + lane]);
        float b = bf2f(Y[s1 * 64 + lane]);
        float c = bf2f(Y[s2 * 64 + lane]);
        float d = bf2f(Y[s3 * 64 + lane]);
        acc += (a + b) + (c + d);
    }
    for (; e < end; e++) acc += bf2f(Y[col[e] * 64 + lane]);
    float deg = (float)(end - beg);
    float hn = (deg > 0.f) ? acc / deg : 0.f;
    float h = Z[node * 64 + lane] + hn;
    H1[node * 64 + lane] = f2bf(tanhf(h));
}

// ---------------- Layer 2 dense: P = h1@Ws2 + b2 (f32), Q = h1@Wn2 (bf16) --------

__global__ __launch_bounds__(128) void k_gemm2(const u16* __restrict__ H1,
                                               const float* __restrict__ Ws2,
                                               const float* __restrict__ b2,
                                               const float* __restrict__ Wn2,
                                               float* __restrict__ P,
                                               u16* __restrict__ Q, int n) {
    __shared__ float ws[256], wn[256], bb[4];
    int t = threadIdx.x;
    for (int i = t; i < 256; i += 128) { ws[i] = Ws2[i]; wn[i] = Wn2[i]; }
    if (t < 4) bb[t] = b2[t];
    __syncthreads();

    int node = blockIdx.x * 128 + t;
    if (node >= n) return;
    const u16* row = H1 + node * 64;
    float p0 = bb[0], p1 = bb[1], p2 = bb[2], p3 = bb[3];
    float q0 = 0.f, q1 = 0.f, q2 = 0.f, q3 = 0.f;
#pragma unroll
    for (int k = 0; k < 64; k += 4) {
        ushort4 hv = *(const ushort4*)(row + k);
        float h0 = bf2f(hv.x), h1v = bf2f(hv.y), h2 = bf2f(hv.z), h3 = bf2f(hv.w);
        const float* w;
        w = &ws[(k + 0) * 4]; p0 += h0 * w[0]; p1 += h0 * w[1]; p2 += h0 * w[2]; p3 += h0 * w[3];
        w = &wn[(k + 0) * 4]; q0 += h0 * w[0]; q1 += h0 * w[1]; q2 += h0 * w[2]; q3 += h0 * w[3];
        w = &ws[(k + 1) * 4]; p0 += h1v * w[0]; p1 += h1v * w[1]; p2 += h1v * w[2]; p3 += h1v * w[3];
        w = &wn[(k + 1) * 4]; q0 += h1v * w[0]; q1 += h1v * w[1]; q2 += h1v * w[2]; q3 += h1v * w[3];
        w = &ws[(k + 2) * 4]; p0 += h2 * w[0]; p1 += h2 * w[1]; p2 += h2 * w[2]; p3 += h2 * w[3];
        w = &wn[(k + 2) * 4]; q0 += h2 * w[0]; q1 += h2 * w[1]; q2 += h2 * w[2]; q3 += h2 * w[3];
        w = &ws[(k + 3) * 4]; p0 += h3 * w[0]; p1 += h3 * w[1]; p2 += h3 * w[2]; p3 += h3 * w[3];
        w = &wn[(k + 3) * 4]; q0 += h3 * w[0]; q1 += h3 * w[1]; q2 += h3 * w[2]; q3 += h3 * w[3];
    }
    *(float4*)(P + node * 4) = make_float4(p0, p1, p2, p3);
    ushort4 qv; qv.x = f2bf(q0); qv.y = f2bf(q1); qv.z = f2bf(q2); qv.w = f2bf(q3);
    *(ushort4*)(Q + node * 4) = qv;
}

// ---------------- Layer 2 aggregate: out = P + mean(Q[neigh])  (f32 out) ---------

__global__ __launch_bounds__(256) void k_gather2(const int* __restrict__ rp,
                                                 const int* __restrict__ col,
                                                 const float* __restrict__ P,
                                                 const u16* __restrict__ Q,
                                                 float* __restrict__ out, int n) {
    int node = blockIdx.x * 256 + threadIdx.x;
    if (node >= n) return;
    int beg = rp[node], end = rp[node + 1];
    float a0 = 0.f, a1 = 0.f, a2 = 0.f, a3 = 0.f;
    for (int e = beg; e < end; e++) {
        int s = col[e];
        ushort4 q = *(const ushort4*)(Q + s * 4);
        a0 += bf2f(q.x); a1 += bf2f(q.y); a2 += bf2f(q.z); a3 += bf2f(q.w);
    }
    float deg = (float)(end - beg);
    float inv = (deg > 0.f) ? 1.f / deg : 0.f;
    float4 p = *(const float4*)(P + node * 4);
    float4 o = make_float4(p.x + a0 * inv, p.y + a1 * inv,
                           p.z + a2 * inv, p.w + a3 * inv);
    *(float4*)(out + node * 4) = o;
}

// ---------------- launch ----------------

extern "C" void kernel_launch(void* const* d_in, const int* in_sizes, int n_in,
                              void* d_out, int out_size, void* d_ws, size_t ws_size,
                              hipStream_t stream) {
    const float* X   = (const float*)d_in[0];
    const int* esrc  = (const int*)d_in[1];
    const int* edst  = (const int*)d_in[2];
    const float* Ws1 = (const float*)d_in[3];
    const float* b1  = (const float*)d_in[4];
    const float* Wn1 = (const float*)d_in[5];
    const float* Ws2 = (const float*)d_in[6];
    const float* b2  = (const float*)d_in[7];
    const float* Wn2 = (const float*)d_in[8];
    float* out = (float*)d_out;

    const int n = in_sizes[0] / 64;   // 100000
    const int E = in_sizes[1];        // 1600000
    const int nb = (n + BKT_NODES - 1) >> BKT_SHIFT;  // 196

    size_t off = 0;
    char* base = (char*)d_ws;
    auto give = [&](size_t bytes) -> char* {
        char* p = base + off;
        off += (bytes + 255) & ~(size_t)255;
        return p;
    };
    int*   row_ptr = (int*)give((size_t)(n + 1) * 4);
    int*   gcnt    = (int*)give((size_t)MAXB * 4);
    int*   boff    = (int*)give((size_t)MAXB * 4);
    int*   gcur    = (int*)give((size_t)MAXB * 4);
    int*   col     = (int*)give((size_t)E * 4);
    float* Z       = (float*)give((size_t)n * 64 * 4);
    u16*   Y       = (u16*)give((size_t)n * 64 * 2);
    u16*   H1      = (u16*)give((size_t)n * 64 * 2);
    float* P       = (float*)give((size_t)n * 4 * 4);
    u16*   Q       = (u16*)give((size_t)n * 4 * 2);
    // binned aliases Z: dead before k_gemm1 writes Z (same stream ordering)
    u32*   binned  = (u32*)Z;

    // --- CSR build ---
    hipMemsetAsync(gcnt, 0, (size_t)MAXB * 4, stream);
    const int chunk = 4096;
    const int nblk = (E + chunk - 1) / chunk;   // 391
    k_hist<<<nblk, 256, 0, stream>>>(edst, gcnt, E, chunk, nb);
    k_bscan<<<1, 256, 0, stream>>>(gcnt, boff, gcur, row_ptr, nb, n, E);
    k_bin<<<nblk, 256, 0, stream>>>(esrc, edst, gcur, binned, E, chunk, nb);
    k_csr<<<nb, 512, 0, stream>>>(binned, boff, row_ptr, col, nb, n, E);

    // --- Layer 1 ---
    k_gemm1<<<1280, 256, 0, stream>>>(X, Ws1, b1, Wn1, Z, Y, n);
    k_gather1<<<(n + 3) / 4, 256, 0, stream>>>(row_ptr, col, Z, Y, H1, n);

    // --- Layer 2 ---
    k_gemm2<<<(n + 127) / 128, 128, 0, stream>>>(H1, Ws2, b2, Wn2, P, Q, n);
    k_gather2<<<(n + 255) / 256, 256, 0, stream>>>(row_ptr, col, P, Q, out, n);
}

// Round 4
// 241.248 us; speedup vs baseline: 1.8712x; 1.2985x over previous
//
#include <hip/hip_runtime.h>
#include <hip/hip_bf16.h>
#include <stdint.h>

typedef unsigned short u16;
typedef unsigned int   u32;
typedef __attribute__((ext_vector_type(8))) short bf16x8;
typedef __attribute__((ext_vector_type(4))) float f32x4;
typedef __attribute__((ext_vector_type(4))) int   i32x4;

#define MAXB 256          // max buckets (n<=131072 with 512-node buckets)
#define BKT_SHIFT 9       // 512 nodes per bucket
#define BKT_NODES 512

__device__ __forceinline__ float bf2f(u16 u) { return __uint_as_float(((u32)u) << 16); }
__device__ __forceinline__ u16 f2bf(float f) {
    u32 u = __float_as_uint(f);
    u += 0x7FFFu + ((u >> 16) & 1u);   // round-nearest-even
    return (u16)(u >> 16);
}
// pack two f32 to bf16 pair by truncation: one v_perm_b32
__device__ __forceinline__ int pkbf(float a, float b) {
    return (int)__builtin_amdgcn_perm(__float_as_uint(b), __float_as_uint(a), 0x07060302u);
}

// ---------------- bucketed CSR build ----------------

__global__ __launch_bounds__(256) void k_hist(const int* __restrict__ dst,
                                              int* __restrict__ gcnt,
                                              int E, int chunk, int nb) {
    __shared__ int h[MAXB];
    int t = threadIdx.x;
    for (int i = t; i < nb; i += 256) h[i] = 0;
    __syncthreads();
    int beg = blockIdx.x * chunk, end = min(beg + chunk, E);
    for (int i = beg + t; i < end; i += 256) atomicAdd(&h[dst[i] >> BKT_SHIFT], 1);
    __syncthreads();
    for (int i = t; i < nb; i += 256) { int c = h[i]; if (c) atomicAdd(&gcnt[i], c); }
}

__global__ void k_bscan(const int* __restrict__ gcnt, int* __restrict__ boff,
                        int* __restrict__ gcur, int* __restrict__ rp,
                        int nb, int n, int E) {
    __shared__ int s[MAXB];
    int t = threadIdx.x;
    if (t < nb) s[t] = gcnt[t];
    __syncthreads();
    if (t == 0) {
        int run = 0;
        for (int b = 0; b < nb; b++) { int v = s[b]; s[b] = run; run += v; }
        rp[n] = E;
    }
    __syncthreads();
    if (t < nb) { boff[t] = s[t]; gcur[t] = s[t]; }
}

__global__ __launch_bounds__(256) void k_bin(const int* __restrict__ src,
                                             const int* __restrict__ dst,
                                             int* __restrict__ gcur,
                                             u32* __restrict__ binned,
                                             int E, int chunk, int nb) {
    __shared__ int h[MAXB], base[MAXB], lcur[MAXB];
    int t = threadIdx.x;
    for (int i = t; i < nb; i += 256) h[i] = 0;
    __syncthreads();
    int beg = blockIdx.x * chunk, end = min(beg + chunk, E);
    for (int i = beg + t; i < end; i += 256) atomicAdd(&h[dst[i] >> BKT_SHIFT], 1);
    __syncthreads();
    for (int i = t; i < nb; i += 256) {
        int c = h[i];
        base[i] = c ? atomicAdd(&gcur[i], c) : 0;
        lcur[i] = 0;
    }
    __syncthreads();
    for (int i = beg + t; i < end; i += 256) {
        int d = dst[i], b = d >> BKT_SHIFT;
        int p = atomicAdd(&lcur[b], 1);
        binned[base[b] + p] = ((u32)src[i] << BKT_SHIFT) | (u32)(d & (BKT_NODES - 1));
    }
}

__global__ __launch_bounds__(512) void k_csr(const u32* __restrict__ binned,
                                             const int* __restrict__ boff,
                                             int* __restrict__ rp,
                                             int* __restrict__ col,
                                             int nb, int n, int E) {
    __shared__ int cnt[BKT_NODES], tmp[BKT_NODES];
    int b = blockIdx.x, t = threadIdx.x;
    int ebeg = boff[b];
    int eend = (b + 1 < nb) ? boff[b + 1] : E;
    cnt[t] = 0;
    __syncthreads();
    for (int i = ebeg + t; i < eend; i += 512)
        atomicAdd(&cnt[binned[i] & (BKT_NODES - 1)], 1);
    __syncthreads();
    int v = cnt[t];
    tmp[t] = v;
    __syncthreads();
    for (int o = 1; o < BKT_NODES; o <<= 1) {
        int y = (t >= o) ? tmp[t - o] : 0;
        __syncthreads();
        tmp[t] += y;
        __syncthreads();
    }
    int excl = tmp[t] - v;
    int gnode = b * BKT_NODES + t;
    if (gnode < n) rp[gnode] = ebeg + excl;
    cnt[t] = excl;   // reuse as cursor
    __syncthreads();
    for (int i = ebeg + t; i < eend; i += 512) {
        u32 e = binned[i];
        int p = atomicAdd(&cnt[e & (BKT_NODES - 1)], 1);
        col[ebeg + p] = (int)(e >> BKT_SHIFT);
    }
}

// ---------------- Layer 1 dense via MFMA ----------------
// Z(:,0:64) = X@Ws1 + b1 (f32), Y(:,0:64) = X@Wn1 (bf16).
// W = [Ws|Wn] staged bf16 in LDS; 16 B-frags held in registers, reused
// across the node loop. One wave per 16-node tile, 16 MFMAs per tile.

__global__ __launch_bounds__(256) void k_gemm1(const float* __restrict__ X,
                                               const float* __restrict__ Ws,
                                               const float* __restrict__ b1,
                                               const float* __restrict__ Wn,
                                               float* __restrict__ Z,
                                               u16* __restrict__ Y, int n) {
    __shared__ u16 wl[64 * 132];   // row stride 132 u16: quad offset 16 banks
    int t = threadIdx.x;
    for (int i = t; i < 8192; i += 256) {
        int k = i >> 7, c = i & 127;
        float w = (c < 64) ? Ws[k * 64 + c] : Wn[k * 64 + (c - 64)];
        wl[k * 132 + c] = f2bf(w);
    }
    __syncthreads();

    int wid = t >> 6, lane = t & 63;
    int lrow = lane & 15, lquad = lane >> 4;

    // B fragments: bfrag[ct][kf][j] = W[kf*32 + lquad*8 + j][ct*16 + lrow]
    bf16x8 bfrag[8][2];
#pragma unroll
    for (int ct = 0; ct < 8; ct++)
#pragma unroll
        for (int kf = 0; kf < 2; kf++)
#pragma unroll
            for (int j = 0; j < 8; j++)
                bfrag[ct][kf][j] = (short)wl[(kf * 32 + lquad * 8 + j) * 132 + ct * 16 + lrow];

    float bias[4];
#pragma unroll
    for (int ct = 0; ct < 4; ct++) bias[ct] = b1[ct * 16 + lrow];

    int tile = blockIdx.x * 4 + wid;
    int tiles = n >> 4;            // n % 16 == 0 (100000)
    if (tile >= tiles) return;
    int nb4 = tile << 4;

    // A fragments: af[kf], lane holds X[nb4+lrow][kf*32 + lquad*8 + j]
    const float* xp = X + (size_t)(nb4 + lrow) * 64 + lquad * 8;
    f32x4 x0 = *(const f32x4*)(xp);
    f32x4 x1 = *(const f32x4*)(xp + 4);
    f32x4 x2 = *(const f32x4*)(xp + 32);
    f32x4 x3 = *(const f32x4*)(xp + 36);
    i32x4 p0, p1;
    p0.x = pkbf(x0.x, x0.y); p0.y = pkbf(x0.z, x0.w);
    p0.z = pkbf(x1.x, x1.y); p0.w = pkbf(x1.z, x1.w);
    p1.x = pkbf(x2.x, x2.y); p1.y = pkbf(x2.z, x2.w);
    p1.z = pkbf(x3.x, x3.y); p1.w = pkbf(x3.z, x3.w);
    bf16x8 af0 = __builtin_bit_cast(bf16x8, p0);
    bf16x8 af1 = __builtin_bit_cast(bf16x8, p1);

    f32x4 acc[8];
#pragma unroll
    for (int ct = 0; ct < 8; ct++) {
        f32x4 c = {0.f, 0.f, 0.f, 0.f};
        c = __builtin_amdgcn_mfma_f32_16x16x32_bf16(af0, bfrag[ct][0], c, 0, 0, 0);
        c = __builtin_amdgcn_mfma_f32_16x16x32_bf16(af1, bfrag[ct][1], c, 0, 0, 0);
        acc[ct] = c;
    }

    // epilogue: C/D layout col=lane&15, row=lquad*4+reg
    int rbase = nb4 + lquad * 4;
#pragma unroll
    for (int ct = 0; ct < 4; ct++)
#pragma unroll
        for (int r = 0; r < 4; r++)
            Z[(size_t)(rbase + r) * 64 + ct * 16 + lrow] = acc[ct][r] + bias[ct];
#pragma unroll
    for (int ct = 0; ct < 4; ct++)
#pragma unroll
        for (int r = 0; r < 4; r++)
            Y[(size_t)(rbase + r) * 64 + ct * 16 + lrow] = f2bf(acc[ct + 4][r]);
}

// ---------------- Layer 1 aggregate: h1 = tanh(Z + mean(Y[neigh])) ----------------

__global__ __launch_bounds__(256) void k_gather1(const int* __restrict__ rp,
                                                 const int* __restrict__ col,
                                                 const float* __restrict__ Z,
                                                 const u16* __restrict__ Y,
                                                 u16* __restrict__ H1, int n) {
    int t = threadIdx.x;
    int wid = t >> 6, lane = t & 63;
    int node = blockIdx.x * 4 + wid;
    if (node >= n) return;
    int beg = rp[node], end = rp[node + 1];
    float acc = 0.f;
    int e = beg;
    for (; e + 4 <= end; e += 4) {
        int s0 = col[e], s1 = col[e + 1], s2 = col[e + 2], s3 = col[e + 3];
        float a = bf2f(Y[s0 * 64 + lane]);
        float b = bf2f(Y[s1 * 64 + lane]);
        float c = bf2f(Y[s2 * 64 + lane]);
        float d = bf2f(Y[s3 * 64 + lane]);
        acc += (a + b) + (c + d);
    }
    for (; e < end; e++) acc += bf2f(Y[col[e] * 64 + lane]);
    float deg = (float)(end - beg);
    float hn = (deg > 0.f) ? acc / deg : 0.f;
    float h = Z[node * 64 + lane] + hn;
    H1[node * 64 + lane] = f2bf(tanhf(h));
}

// ---------------- Layer 2 dense: P = h1@Ws2 + b2 (f32), Q = h1@Wn2 (bf16) --------

__global__ __launch_bounds__(128) void k_gemm2(const u16* __restrict__ H1,
                                               const float* __restrict__ Ws2,
                                               const float* __restrict__ b2,
                                               const float* __restrict__ Wn2,
                                               float* __restrict__ P,
                                               u16* __restrict__ Q, int n) {
    __shared__ float ws[256], wn[256], bb[4];
    int t = threadIdx.x;
    for (int i = t; i < 256; i += 128) { ws[i] = Ws2[i]; wn[i] = Wn2[i]; }
    if (t < 4) bb[t] = b2[t];
    __syncthreads();

    int node = blockIdx.x * 128 + t;
    if (node >= n) return;
    const u16* row = H1 + node * 64;
    float p0 = bb[0], p1 = bb[1], p2 = bb[2], p3 = bb[3];
    float q0 = 0.f, q1 = 0.f, q2 = 0.f, q3 = 0.f;
#pragma unroll
    for (int k = 0; k < 64; k += 4) {
        ushort4 hv = *(const ushort4*)(row + k);
        float h0 = bf2f(hv.x), h1v = bf2f(hv.y), h2 = bf2f(hv.z), h3 = bf2f(hv.w);
        const float* w;
        w = &ws[(k + 0) * 4]; p0 += h0 * w[0]; p1 += h0 * w[1]; p2 += h0 * w[2]; p3 += h0 * w[3];
        w = &wn[(k + 0) * 4]; q0 += h0 * w[0]; q1 += h0 * w[1]; q2 += h0 * w[2]; q3 += h0 * w[3];
        w = &ws[(k + 1) * 4]; p0 += h1v * w[0]; p1 += h1v * w[1]; p2 += h1v * w[2]; p3 += h1v * w[3];
        w = &wn[(k + 1) * 4]; q0 += h1v * w[0]; q1 += h1v * w[1]; q2 += h1v * w[2]; q3 += h1v * w[3];
        w = &ws[(k + 2) * 4]; p0 += h2 * w[0]; p1 += h2 * w[1]; p2 += h2 * w[2]; p3 += h2 * w[3];
        w = &wn[(k + 2) * 4]; q0 += h2 * w[0]; q1 += h2 * w[1]; q2 += h2 * w[2]; q3 += h2 * w[3];
        w = &ws[(k + 3) * 4]; p0 += h3 * w[0]; p1 += h3 * w[1]; p2 += h3 * w[2]; p3 += h3 * w[3];
        w = &wn[(k + 3) * 4]; q0 += h3 * w[0]; q1 += h3 * w[1]; q2 += h3 * w[2]; q3 += h3 * w[3];
    }
    *(float4*)(P + node * 4) = make_float4(p0, p1, p2, p3);
    ushort4 qv; qv.x = f2bf(q0); qv.y = f2bf(q1); qv.z = f2bf(q2); qv.w = f2bf(q3);
    *(ushort4*)(Q + node * 4) = qv;
}

// ---------------- Layer 2 aggregate: out = P + mean(Q[neigh])  (f32 out) ---------

__global__ __launch_bounds__(256) void k_gather2(const int* __restrict__ rp,
                                                 const int* __restrict__ col,
                                                 const float* __restrict__ P,
                                                 const u16* __restrict__ Q,
                                                 float* __restrict__ out, int n) {
    int node = blockIdx.x * 256 + threadIdx.x;
    if (node >= n) return;
    int beg = rp[node], end = rp[node + 1];
    float a0 = 0.f, a1 = 0.f, a2 = 0.f, a3 = 0.f;
    for (int e = beg; e < end; e++) {
        int s = col[e];
        ushort4 q = *(const ushort4*)(Q + s * 4);
        a0 += bf2f(q.x); a1 += bf2f(q.y); a2 += bf2f(q.z); a3 += bf2f(q.w);
    }
    float deg = (float)(end - beg);
    float inv = (deg > 0.f) ? 1.f / deg : 0.f;
    float4 p = *(const float4*)(P + node * 4);
    float4 o = make_float4(p.x + a0 * inv, p.y + a1 * inv,
                           p.z + a2 * inv, p.w + a3 * inv);
    *(float4*)(out + node * 4) = o;
}

// ---------------- launch ----------------

extern "C" void kernel_launch(void* const* d_in, const int* in_sizes, int n_in,
                              void* d_out, int out_size, void* d_ws, size_t ws_size,
                              hipStream_t stream) {
    const float* X   = (const float*)d_in[0];
    const int* esrc  = (const int*)d_in[1];
    const int* edst  = (const int*)d_in[2];
    const float* Ws1 = (const float*)d_in[3];
    const float* b1  = (const float*)d_in[4];
    const float* Wn1 = (const float*)d_in[5];
    const float* Ws2 = (const float*)d_in[6];
    const float* b2  = (const float*)d_in[7];
    const float* Wn2 = (const float*)d_in[8];
    float* out = (float*)d_out;

    const int n = in_sizes[0] / 64;   // 100000
    const int E = in_sizes[1];        // 1600000
    const int nb = (n + BKT_NODES - 1) >> BKT_SHIFT;  // 196

    size_t off = 0;
    char* base = (char*)d_ws;
    auto give = [&](size_t bytes) -> char* {
        char* p = base + off;
        off += (bytes + 255) & ~(size_t)255;
        return p;
    };
    int*   row_ptr = (int*)give((size_t)(n + 1) * 4);
    int*   gcnt    = (int*)give((size_t)MAXB * 4);
    int*   boff    = (int*)give((size_t)MAXB * 4);
    int*   gcur    = (int*)give((size_t)MAXB * 4);
    int*   col     = (int*)give((size_t)E * 4);
    float* Z       = (float*)give((size_t)n * 64 * 4);
    u16*   Y       = (u16*)give((size_t)n * 64 * 2);
    u16*   H1      = (u16*)give((size_t)n * 64 * 2);
    float* P       = (float*)give((size_t)n * 4 * 4);
    u16*   Q       = (u16*)give((size_t)n * 4 * 2);
    // binned aliases Z: consumed by k_csr before k_gemm1 writes Z
    u32*   binned  = (u32*)Z;

    // --- CSR build ---
    hipMemsetAsync(gcnt, 0, (size_t)MAXB * 4, stream);
    const int chunk = 4096;
    const int nblk = (E + chunk - 1) / chunk;   // 391
    k_hist<<<nblk, 256, 0, stream>>>(edst, gcnt, E, chunk, nb);
    k_bscan<<<1, 256, 0, stream>>>(gcnt, boff, gcur, row_ptr, nb, n, E);
    k_bin<<<nblk, 256, 0, stream>>>(esrc, edst, gcur, binned, E, chunk, nb);
    k_csr<<<nb, 512, 0, stream>>>(binned, boff, row_ptr, col, nb, n, E);

    // --- Layer 1 ---
    int tiles = n >> 4;                       // 6250
    k_gemm1<<<(tiles + 3) / 4, 256, 0, stream>>>(X, Ws1, b1, Wn1, Z, Y, n);
    k_gather1<<<(n + 3) / 4, 256, 0, stream>>>(row_ptr, col, Z, Y, H1, n);

    // --- Layer 2 ---
    k_gemm2<<<(n + 127) / 128, 128, 0, stream>>>(H1, Ws2, b2, Wn2, P, Q, n);
    k_gather2<<<(n + 255) / 256, 256, 0, stream>>>(row_ptr, col, P, Q, out, n);
}

// Round 5
// 216.887 us; speedup vs baseline: 2.0813x; 1.1123x over previous
//
#include <hip/hip_runtime.h>
#include <hip/hip_bf16.h>
#include <stdint.h>

typedef unsigned short u16;
typedef unsigned int   u32;
typedef __attribute__((ext_vector_type(8))) short bf16x8;
typedef __attribute__((ext_vector_type(4))) float f32x4;
typedef __attribute__((ext_vector_type(4))) int   i32x4;

#define MAXB 256          // max buckets (n<=131072 with 512-node buckets)
#define BKT_SHIFT 9       // 512 nodes per bucket
#define BKT_NODES 512

__device__ __forceinline__ float bf2f(u16 u) { return __uint_as_float(((u32)u) << 16); }
__device__ __forceinline__ u16 f2bf(float f) {
    u32 u = __float_as_uint(f);
    u += 0x7FFFu + ((u >> 16) & 1u);   // round-nearest-even
    return (u16)(u >> 16);
}
// pack two f32 to bf16 pair by truncation: one v_perm_b32
__device__ __forceinline__ int pkbf(float a, float b) {
    return (int)__builtin_amdgcn_perm(__float_as_uint(b), __float_as_uint(a), 0x07060302u);
}

// ---------------- bucketed CSR build ----------------

__global__ __launch_bounds__(256) void k_hist(const int* __restrict__ dst,
                                              int* __restrict__ gcnt,
                                              int E, int chunk, int nb) {
    __shared__ int h[MAXB];
    int t = threadIdx.x;
    for (int i = t; i < nb; i += 256) h[i] = 0;
    __syncthreads();
    int beg = blockIdx.x * chunk, end = min(beg + chunk, E);
    for (int i = beg + t; i < end; i += 256) atomicAdd(&h[dst[i] >> BKT_SHIFT], 1);
    __syncthreads();
    for (int i = t; i < nb; i += 256) { int c = h[i]; if (c) atomicAdd(&gcnt[i], c); }
}

__global__ void k_bscan(const int* __restrict__ gcnt, int* __restrict__ boff,
                        int* __restrict__ gcur, int* __restrict__ rp,
                        int nb, int n, int E) {
    __shared__ int s[MAXB];
    int t = threadIdx.x;
    if (t < nb) s[t] = gcnt[t];
    __syncthreads();
    if (t == 0) {
        int run = 0;
        for (int b = 0; b < nb; b++) { int v = s[b]; s[b] = run; run += v; }
        rp[n] = E;
    }
    __syncthreads();
    if (t < nb) { boff[t] = s[t]; gcur[t] = s[t]; }
}

__global__ __launch_bounds__(256) void k_bin(const int* __restrict__ src,
                                             const int* __restrict__ dst,
                                             int* __restrict__ gcur,
                                             u32* __restrict__ binned,
                                             int E, int chunk, int nb) {
    __shared__ int h[MAXB], base[MAXB], lcur[MAXB];
    int t = threadIdx.x;
    for (int i = t; i < nb; i += 256) h[i] = 0;
    __syncthreads();
    int beg = blockIdx.x * chunk, end = min(beg + chunk, E);
    for (int i = beg + t; i < end; i += 256) atomicAdd(&h[dst[i] >> BKT_SHIFT], 1);
    __syncthreads();
    for (int i = t; i < nb; i += 256) {
        int c = h[i];
        base[i] = c ? atomicAdd(&gcur[i], c) : 0;
        lcur[i] = 0;
    }
    __syncthreads();
    for (int i = beg + t; i < end; i += 256) {
        int d = dst[i], b = d >> BKT_SHIFT;
        int p = atomicAdd(&lcur[b], 1);
        binned[base[b] + p] = ((u32)src[i] << BKT_SHIFT) | (u32)(d & (BKT_NODES - 1));
    }
}

__global__ __launch_bounds__(512) void k_csr(const u32* __restrict__ binned,
                                             const int* __restrict__ boff,
                                             int* __restrict__ rp,
                                             int* __restrict__ col,
                                             int nb, int n, int E) {
    __shared__ int cnt[BKT_NODES], tmp[BKT_NODES];
    int b = blockIdx.x, t = threadIdx.x;
    int ebeg = boff[b];
    int eend = (b + 1 < nb) ? boff[b + 1] : E;
    cnt[t] = 0;
    __syncthreads();
    for (int i = ebeg + t; i < eend; i += 512)
        atomicAdd(&cnt[binned[i] & (BKT_NODES - 1)], 1);
    __syncthreads();
    int v = cnt[t];
    tmp[t] = v;
    __syncthreads();
    for (int o = 1; o < BKT_NODES; o <<= 1) {
        int y = (t >= o) ? tmp[t - o] : 0;
        __syncthreads();
        tmp[t] += y;
        __syncthreads();
    }
    int excl = tmp[t] - v;
    int gnode = b * BKT_NODES + t;
    if (gnode < n) rp[gnode] = ebeg + excl;
    cnt[t] = excl;   // reuse as cursor
    __syncthreads();
    for (int i = ebeg + t; i < eend; i += 512) {
        u32 e = binned[i];
        int p = atomicAdd(&cnt[e & (BKT_NODES - 1)], 1);
        col[ebeg + p] = (int)(e >> BKT_SHIFT);
    }
}

// ---------------- Layer 1 dense via MFMA ----------------
// Zb = bf16(X@Ws1 + b1), Y = bf16(X@Wn1).

__global__ __launch_bounds__(256) void k_gemm1(const float* __restrict__ X,
                                               const float* __restrict__ Ws,
                                               const float* __restrict__ b1,
                                               const float* __restrict__ Wn,
                                               u16* __restrict__ Zb,
                                               u16* __restrict__ Y, int n) {
    __shared__ u16 wl[64 * 132];   // row stride 132 u16
    int t = threadIdx.x;
    for (int i = t; i < 8192; i += 256) {
        int k = i >> 7, c = i & 127;
        float w = (c < 64) ? Ws[k * 64 + c] : Wn[k * 64 + (c - 64)];
        wl[k * 132 + c] = f2bf(w);
    }
    __syncthreads();

    int wid = t >> 6, lane = t & 63;
    int lrow = lane & 15, lquad = lane >> 4;

    bf16x8 bfrag[8][2];
#pragma unroll
    for (int ct = 0; ct < 8; ct++)
#pragma unroll
        for (int kf = 0; kf < 2; kf++)
#pragma unroll
            for (int j = 0; j < 8; j++)
                bfrag[ct][kf][j] = (short)wl[(kf * 32 + lquad * 8 + j) * 132 + ct * 16 + lrow];

    float bias[4];
#pragma unroll
    for (int ct = 0; ct < 4; ct++) bias[ct] = b1[ct * 16 + lrow];

    int tile = blockIdx.x * 4 + wid;
    int tiles = n >> 4;            // n % 16 == 0 (100000)
    if (tile >= tiles) return;
    int nb4 = tile << 4;

    const float* xp = X + (size_t)(nb4 + lrow) * 64 + lquad * 8;
    f32x4 x0 = *(const f32x4*)(xp);
    f32x4 x1 = *(const f32x4*)(xp + 4);
    f32x4 x2 = *(const f32x4*)(xp + 32);
    f32x4 x3 = *(const f32x4*)(xp + 36);
    i32x4 p0, p1;
    p0.x = pkbf(x0.x, x0.y); p0.y = pkbf(x0.z, x0.w);
    p0.z = pkbf(x1.x, x1.y); p0.w = pkbf(x1.z, x1.w);
    p1.x = pkbf(x2.x, x2.y); p1.y = pkbf(x2.z, x2.w);
    p1.z = pkbf(x3.x, x3.y); p1.w = pkbf(x3.z, x3.w);
    bf16x8 af0 = __builtin_bit_cast(bf16x8, p0);
    bf16x8 af1 = __builtin_bit_cast(bf16x8, p1);

    f32x4 acc[8];
#pragma unroll
    for (int ct = 0; ct < 8; ct++) {
        f32x4 c = {0.f, 0.f, 0.f, 0.f};
        c = __builtin_amdgcn_mfma_f32_16x16x32_bf16(af0, bfrag[ct][0], c, 0, 0, 0);
        c = __builtin_amdgcn_mfma_f32_16x16x32_bf16(af1, bfrag[ct][1], c, 0, 0, 0);
        acc[ct] = c;
    }

    int rbase = nb4 + lquad * 4;
#pragma unroll
    for (int ct = 0; ct < 4; ct++)
#pragma unroll
        for (int r = 0; r < 4; r++)
            Zb[(size_t)(rbase + r) * 64 + ct * 16 + lrow] = f2bf(acc[ct][r] + bias[ct]);
#pragma unroll
    for (int ct = 0; ct < 4; ct++)
#pragma unroll
        for (int r = 0; r < 4; r++)
            Y[(size_t)(rbase + r) * 64 + ct * 16 + lrow] = f2bf(acc[ct + 4][r]);
}

// ---------------- Layer 1 aggregate: h1 = tanh(Zb + mean(Y[neigh])) ----------------
// Quarter-wave per node: 16 lanes x ushort4 = one 128B Y row per load.
// 4 independent edge streams per wave x 4-deep unroll = 16 outstanding loads.

__global__ __launch_bounds__(256) void k_gather1(const int* __restrict__ rp,
                                                 const int* __restrict__ col,
                                                 const u16* __restrict__ Zb,
                                                 const u16* __restrict__ Y,
                                                 u16* __restrict__ H1, int n) {
    int t = threadIdx.x;
    int q = t >> 4;          // quarter-wave id in block: 0..15
    int l = t & 15;          // lane in quarter
    int node = blockIdx.x * 16 + q;
    if (node >= n) return;
    int beg = rp[node], end = rp[node + 1];
    float a0 = 0.f, a1 = 0.f, a2 = 0.f, a3 = 0.f;
    int e = beg;
    for (; e + 4 <= end; e += 4) {
        int s0 = col[e], s1 = col[e + 1], s2 = col[e + 2], s3 = col[e + 3];
        ushort4 r0 = *(const ushort4*)(Y + (size_t)s0 * 64 + l * 4);
        ushort4 r1 = *(const ushort4*)(Y + (size_t)s1 * 64 + l * 4);
        ushort4 r2 = *(const ushort4*)(Y + (size_t)s2 * 64 + l * 4);
        ushort4 r3 = *(const ushort4*)(Y + (size_t)s3 * 64 + l * 4);
        a0 += bf2f(r0.x) + bf2f(r1.x) + bf2f(r2.x) + bf2f(r3.x);
        a1 += bf2f(r0.y) + bf2f(r1.y) + bf2f(r2.y) + bf2f(r3.y);
        a2 += bf2f(r0.z) + bf2f(r1.z) + bf2f(r2.z) + bf2f(r3.z);
        a3 += bf2f(r0.w) + bf2f(r1.w) + bf2f(r2.w) + bf2f(r3.w);
    }
    for (; e < end; e++) {
        ushort4 r = *(const ushort4*)(Y + (size_t)col[e] * 64 + l * 4);
        a0 += bf2f(r.x); a1 += bf2f(r.y); a2 += bf2f(r.z); a3 += bf2f(r.w);
    }
    float deg = (float)(end - beg);
    float inv = (deg > 0.f) ? 1.f / deg : 0.f;
    ushort4 z = *(const ushort4*)(Zb + (size_t)node * 64 + l * 4);
    ushort4 h;
    h.x = f2bf(tanhf(bf2f(z.x) + a0 * inv));
    h.y = f2bf(tanhf(bf2f(z.y) + a1 * inv));
    h.z = f2bf(tanhf(bf2f(z.z) + a2 * inv));
    h.w = f2bf(tanhf(bf2f(z.w) + a3 * inv));
    *(ushort4*)(H1 + (size_t)node * 64 + l * 4) = h;
}

// ---------------- Layer 2 dense: P = h1@Ws2 + b2 (f32), Q = h1@Wn2 (bf16) --------

__global__ __launch_bounds__(128) void k_gemm2(const u16* __restrict__ H1,
                                               const float* __restrict__ Ws2,
                                               const float* __restrict__ b2,
                                               const float* __restrict__ Wn2,
                                               float* __restrict__ P,
                                               u16* __restrict__ Q, int n) {
    __shared__ float ws[256], wn[256], bb[4];
    int t = threadIdx.x;
    for (int i = t; i < 256; i += 128) { ws[i] = Ws2[i]; wn[i] = Wn2[i]; }
    if (t < 4) bb[t] = b2[t];
    __syncthreads();

    int node = blockIdx.x * 128 + t;
    if (node >= n) return;
    const u16* row = H1 + node * 64;
    float p0 = bb[0], p1 = bb[1], p2 = bb[2], p3 = bb[3];
    float q0 = 0.f, q1 = 0.f, q2 = 0.f, q3 = 0.f;
#pragma unroll
    for (int k = 0; k < 64; k += 4) {
        ushort4 hv = *(const ushort4*)(row + k);
        float h0 = bf2f(hv.x), h1v = bf2f(hv.y), h2 = bf2f(hv.z), h3 = bf2f(hv.w);
        const float* w;
        w = &ws[(k + 0) * 4]; p0 += h0 * w[0]; p1 += h0 * w[1]; p2 += h0 * w[2]; p3 += h0 * w[3];
        w = &wn[(k + 0) * 4]; q0 += h0 * w[0]; q1 += h0 * w[1]; q2 += h0 * w[2]; q3 += h0 * w[3];
        w = &ws[(k + 1) * 4]; p0 += h1v * w[0]; p1 += h1v * w[1]; p2 += h1v * w[2]; p3 += h1v * w[3];
        w = &wn[(k + 1) * 4]; q0 += h1v * w[0]; q1 += h1v * w[1]; q2 += h1v * w[2]; q3 += h1v * w[3];
        w = &ws[(k + 2) * 4]; p0 += h2 * w[0]; p1 += h2 * w[1]; p2 += h2 * w[2]; p3 += h2 * w[3];
        w = &wn[(k + 2) * 4]; q0 += h2 * w[0]; q1 += h2 * w[1]; q2 += h2 * w[2]; q3 += h2 * w[3];
        w = &ws[(k + 3) * 4]; p0 += h3 * w[0]; p1 += h3 * w[1]; p2 += h3 * w[2]; p3 += h3 * w[3];
        w = &wn[(k + 3) * 4]; q0 += h3 * w[0]; q1 += h3 * w[1]; q2 += h3 * w[2]; q3 += h3 * w[3];
    }
    *(float4*)(P + node * 4) = make_float4(p0, p1, p2, p3);
    ushort4 qv; qv.x = f2bf(q0); qv.y = f2bf(q1); qv.z = f2bf(q2); qv.w = f2bf(q3);
    *(ushort4*)(Q + node * 4) = qv;
}

// ---------------- Layer 2 aggregate: out = P + mean(Q[neigh])  (f32 out) ---------

__global__ __launch_bounds__(256) void k_gather2(const int* __restrict__ rp,
                                                 const int* __restrict__ col,
                                                 const float* __restrict__ P,
                                                 const u16* __restrict__ Q,
                                                 float* __restrict__ out, int n) {
    int node = blockIdx.x * 256 + threadIdx.x;
    if (node >= n) return;
    int beg = rp[node], end = rp[node + 1];
    float a0 = 0.f, a1 = 0.f, a2 = 0.f, a3 = 0.f;
    for (int e = beg; e < end; e++) {
        int s = col[e];
        ushort4 q = *(const ushort4*)(Q + s * 4);
        a0 += bf2f(q.x); a1 += bf2f(q.y); a2 += bf2f(q.z); a3 += bf2f(q.w);
    }
    float deg = (float)(end - beg);
    float inv = (deg > 0.f) ? 1.f / deg : 0.f;
    float4 p = *(const float4*)(P + node * 4);
    float4 o = make_float4(p.x + a0 * inv, p.y + a1 * inv,
                           p.z + a2 * inv, p.w + a3 * inv);
    *(float4*)(out + node * 4) = o;
}

// ---------------- launch ----------------

extern "C" void kernel_launch(void* const* d_in, const int* in_sizes, int n_in,
                              void* d_out, int out_size, void* d_ws, size_t ws_size,
                              hipStream_t stream) {
    const float* X   = (const float*)d_in[0];
    const int* esrc  = (const int*)d_in[1];
    const int* edst  = (const int*)d_in[2];
    const float* Ws1 = (const float*)d_in[3];
    const float* b1  = (const float*)d_in[4];
    const float* Wn1 = (const float*)d_in[5];
    const float* Ws2 = (const float*)d_in[6];
    const float* b2  = (const float*)d_in[7];
    const float* Wn2 = (const float*)d_in[8];
    float* out = (float*)d_out;

    const int n = in_sizes[0] / 64;   // 100000
    const int E = in_sizes[1];        // 1600000
    const int nb = (n + BKT_NODES - 1) >> BKT_SHIFT;  // 196

    size_t off = 0;
    char* base = (char*)d_ws;
    auto give = [&](size_t bytes) -> char* {
        char* p = base + off;
        off += (bytes + 255) & ~(size_t)255;
        return p;
    };
    int*   row_ptr = (int*)give((size_t)(n + 1) * 4);
    int*   gcnt    = (int*)give((size_t)MAXB * 4);
    int*   boff    = (int*)give((size_t)MAXB * 4);
    int*   gcur    = (int*)give((size_t)MAXB * 4);
    int*   col     = (int*)give((size_t)E * 4);
    u16*   Zb      = (u16*)give((size_t)n * 64 * 4);  // f32-sized region; low half used, aliases binned
    u16*   Y       = (u16*)give((size_t)n * 64 * 2);
    u16*   H1      = (u16*)give((size_t)n * 64 * 2);
    float* P       = (float*)give((size_t)n * 4 * 4);
    u16*   Q       = (u16*)give((size_t)n * 4 * 2);
    // binned aliases Zb region: consumed by k_csr before k_gemm1 writes Zb
    u32*   binned  = (u32*)Zb;

    // --- CSR build ---
    hipMemsetAsync(gcnt, 0, (size_t)MAXB * 4, stream);
    const int chunk = 4096;
    const int nblk = (E + chunk - 1) / chunk;   // 391
    k_hist<<<nblk, 256, 0, stream>>>(edst, gcnt, E, chunk, nb);
    k_bscan<<<1, 256, 0, stream>>>(gcnt, boff, gcur, row_ptr, nb, n, E);
    k_bin<<<nblk, 256, 0, stream>>>(esrc, edst, gcur, binned, E, chunk, nb);
    k_csr<<<nb, 512, 0, stream>>>(binned, boff, row_ptr, col, nb, n, E);

    // --- Layer 1 ---
    int tiles = n >> 4;                       // 6250
    k_gemm1<<<(tiles + 3) / 4, 256, 0, stream>>>(X, Ws1, b1, Wn1, Zb, Y, n);
    k_gather1<<<(n + 15) / 16, 256, 0, stream>>>(row_ptr, col, Zb, Y, H1, n);

    // --- Layer 2 ---
    k_gemm2<<<(n + 127) / 128, 128, 0, stream>>>(H1, Ws2, b2, Wn2, P, Q, n);
    k_gather2<<<(n + 255) / 256, 256, 0, stream>>>(row_ptr, col, P, Q, out, n);
}